// Round 1
// baseline (3585.192 us; speedup 1.0000x reference)
//
#include <hip/hip_runtime.h>
#include <math.h>

#define NCLS   80
#define NPROP  1000
#define FCDIM  1024
#define DFLAT  12544   // 256*7*7
#define MAXR   4.1351665567423560f

// ---------------------------------------------------------------------------
// RoI Align: one block per RoI, one thread per channel (256).
// Sample coordinates (14 per axis) precomputed in LDS.
// ---------------------------------------------------------------------------
__global__ __launch_bounds__(256) void roi_align_k(
    const float* __restrict__ f0, const float* __restrict__ f1,
    const float* __restrict__ f2, const float* __restrict__ f3,
    const float* __restrict__ props, float* __restrict__ out, int roiStart)
{
    int r = roiStart + blockIdx.x;
    const float4 p = *(const float4*)&props[(size_t)r * 4];

    float wp = p.z - p.x, hp = p.w - p.y;
    float scale = sqrtf(fmaxf(wp * hp, 1e-6f));
    int lvl = (int)floorf(log2f(scale / 56.0f + 1e-6f));
    lvl = min(max(lvl, 0), 3);

    const float* f; int H, W; float sc;
    switch (lvl) {
        case 0:  f = f0; H = 200; W = 336; sc = 0.25f;    break;
        case 1:  f = f1; H = 100; W = 168; sc = 0.125f;   break;
        case 2:  f = f2; H = 50;  W = 84;  sc = 0.0625f;  break;
        default: f = f3; H = 25;  W = 42;  sc = 0.03125f; break;
    }

    __shared__ int   sx0[14], sx1[14], sy0[14], sy1[14];
    __shared__ float slx[14], sly[14];
    __shared__ unsigned char svx[14], svy[14];

    int t = threadIdx.x;
    if (t < 28) {
        bool isx = t < 14;
        int i = isx ? t : t - 14;
        float start = (isx ? p.x : p.y) * sc - 0.5f;
        float range = (isx ? (p.z - p.x) : (p.w - p.y)) * sc;
        int lim = isx ? W : H;
        float pos = start + (((float)i + 0.5f) / 14.0f) * range;
        float fl  = floorf(pos);
        float frac = pos - fl;
        int i0 = (int)fl;
        i0 = min(max(i0, 0), lim - 1);
        int i1 = min(i0 + 1, lim - 1);
        unsigned char v = (pos >= -1.0f) && (pos <= (float)lim);
        if (isx) { sx0[i] = i0; sx1[i] = i1; slx[i] = frac; svx[i] = v; }
        else     { sy0[i] = i0; sy1[i] = i1; sly[i] = frac; svy[i] = v; }
    }
    __syncthreads();

    const float* fc_ = f + (size_t)t * (H * W);
    float* op = out + (size_t)blockIdx.x * DFLAT + (size_t)t * 49;

    for (int ph = 0; ph < 7; ph++) {
        for (int pw = 0; pw < 7; pw++) {
            float acc = 0.f;
            #pragma unroll
            for (int iy = 0; iy < 2; iy++) {
                int yi = ph * 2 + iy;
                float ly = sly[yi]; int y0 = sy0[yi], y1 = sy1[yi];
                bool vy = svy[yi];
                #pragma unroll
                for (int ix = 0; ix < 2; ix++) {
                    int xi = pw * 2 + ix;
                    if (vy && svx[xi]) {
                        float lx = slx[xi]; int x0 = sx0[xi], x1 = sx1[xi];
                        float v00 = fc_[y0 * W + x0], v01 = fc_[y0 * W + x1];
                        float v10 = fc_[y1 * W + x0], v11 = fc_[y1 * W + x1];
                        acc += (1.f - ly) * ((1.f - lx) * v00 + lx * v01)
                             +        ly  * ((1.f - lx) * v10 + lx * v11);
                    }
                }
            }
            op[ph * 7 + pw] = acc * 0.25f;
        }
    }
}

// ---------------------------------------------------------------------------
// GEMM: C(MxN) = A(MxK) * W(NxK)^T + bias, optional ReLU. fp32, 64x64x16 tile.
// ---------------------------------------------------------------------------
__global__ __launch_bounds__(256) void gemm_tn_k(
    const float* __restrict__ A, const float* __restrict__ W,
    const float* __restrict__ bias, float* __restrict__ C,
    int M, int N, int K, int relu)
{
    __shared__ float As[16][64];
    __shared__ float Bs[16][64];

    int tid = threadIdx.x;
    int tx = tid & 15;       // n-dir (4 cols each)
    int ty = tid >> 4;       // m-dir (4 rows each)
    int m0 = blockIdx.y * 64, n0 = blockIdx.x * 64;

    int lr = tid >> 2;            // row within tile 0..63
    int lk = (tid & 3) << 2;      // k offset 0,4,8,12

    const float* Arow = A + (size_t)(m0 + lr) * K + lk;
    const float* Wrow = W + (size_t)(n0 + lr) * K + lk;
    bool mOK = (m0 + lr) < M;
    bool nOK = (n0 + lr) < N;

    float acc[4][4] = {};

    for (int k0 = 0; k0 < K; k0 += 16) {
        float4 av = mOK ? *(const float4*)(Arow + k0) : make_float4(0.f, 0.f, 0.f, 0.f);
        float4 wv = nOK ? *(const float4*)(Wrow + k0) : make_float4(0.f, 0.f, 0.f, 0.f);
        As[lk + 0][lr] = av.x; As[lk + 1][lr] = av.y;
        As[lk + 2][lr] = av.z; As[lk + 3][lr] = av.w;
        Bs[lk + 0][lr] = wv.x; Bs[lk + 1][lr] = wv.y;
        Bs[lk + 2][lr] = wv.z; Bs[lk + 3][lr] = wv.w;
        __syncthreads();

        #pragma unroll
        for (int kk = 0; kk < 16; kk++) {
            float4 a = *(const float4*)&As[kk][ty << 2];
            float4 b = *(const float4*)&Bs[kk][tx << 2];
            acc[0][0] += a.x * b.x; acc[0][1] += a.x * b.y;
            acc[0][2] += a.x * b.z; acc[0][3] += a.x * b.w;
            acc[1][0] += a.y * b.x; acc[1][1] += a.y * b.y;
            acc[1][2] += a.y * b.z; acc[1][3] += a.y * b.w;
            acc[2][0] += a.z * b.x; acc[2][1] += a.z * b.y;
            acc[2][2] += a.z * b.z; acc[2][3] += a.z * b.w;
            acc[3][0] += a.w * b.x; acc[3][1] += a.w * b.y;
            acc[3][2] += a.w * b.z; acc[3][3] += a.w * b.w;
        }
        __syncthreads();
    }

    #pragma unroll
    for (int i = 0; i < 4; i++) {
        int m = m0 + (ty << 2) + i;
        if (m >= M) continue;
        #pragma unroll
        for (int j = 0; j < 4; j++) {
            int n = n0 + (tx << 2) + j;
            if (n < N) {
                float v = acc[i][j] + bias[n];
                if (relu) v = fmaxf(v, 0.f);
                C[(size_t)m * N + n] = v;
            }
        }
    }
}

// ---------------------------------------------------------------------------
// Softmax over 81 classes + delta2bbox (80 classes). One block per RoI.
// Writes class-major probsT[80][1000] and boxesT[80][1000][4].
// ---------------------------------------------------------------------------
__global__ __launch_bounds__(128) void head_post_k(
    const float* __restrict__ cls_s, const float* __restrict__ reg_s,
    const float* __restrict__ props,
    float* __restrict__ probsT, float* __restrict__ boxesT)
{
    int r = blockIdx.x, t = threadIdx.x;
    __shared__ float red[128];

    float x = (t < 81) ? cls_s[(size_t)r * 81 + t] : -1e30f;
    red[t] = x; __syncthreads();
    for (int s = 64; s > 0; s >>= 1) {
        if (t < s) red[t] = fmaxf(red[t], red[t + s]);
        __syncthreads();
    }
    float mx = red[0];
    __syncthreads();

    float e = (t < 81) ? expf(x - mx) : 0.f;
    red[t] = e; __syncthreads();
    for (int s = 64; s > 0; s >>= 1) {
        if (t < s) red[t] += red[t + s];
        __syncthreads();
    }
    float inv = 1.f / red[0];

    if (t < NCLS) {
        probsT[(size_t)t * NPROP + r] = e * inv;

        const float4 p = *(const float4*)&props[(size_t)r * 4];
        float4 d = *(const float4*)&reg_s[(size_t)r * 320 + t * 4];
        float dx = d.x * 0.1f, dy = d.y * 0.1f;
        float dw = fminf(fmaxf(d.z * 0.2f, -MAXR), MAXR);
        float dh = fminf(fmaxf(d.w * 0.2f, -MAXR), MAXR);
        float px = (p.x + p.z) * 0.5f, py = (p.y + p.w) * 0.5f;
        float pw = p.z - p.x, ph = p.w - p.y;
        float gw = pw * expf(dw), gh = ph * expf(dh);
        float gx = px + pw * dx, gy = py + ph * dy;
        float4 bo = make_float4(gx - gw * 0.5f, gy - gh * 0.5f,
                                gx + gw * 0.5f, gy + gh * 0.5f);
        *(float4*)&boxesT[(size_t)(t * NPROP + r) * 4] = bo;
    }
}

// ---------------------------------------------------------------------------
// Per-class stable descending sort (bitonic on (score desc, idx asc)).
// One block (512 thr) per class; 1000 real + 24 pad elements.
// ---------------------------------------------------------------------------
__global__ __launch_bounds__(512) void sort_k(
    const float* __restrict__ probsT, const float* __restrict__ boxesT,
    float* __restrict__ sortedS, float* __restrict__ sortedB)
{
    int c = blockIdx.x, t = threadIdx.x;
    __shared__ float sk[1024];
    __shared__ int   si[1024];

    for (int j = t; j < 1024; j += 512) {
        sk[j] = (j < NPROP) ? probsT[(size_t)c * NPROP + j] : -1e30f;
        si[j] = j;
    }
    __syncthreads();

    for (int size = 2; size <= 1024; size <<= 1) {
        for (int stride = size >> 1; stride > 0; stride >>= 1) {
            int i = (t << 1) - (t & (stride - 1));
            int j = i + stride;
            float ka = sk[i], kb = sk[j];
            int ia = si[i], ib = si[j];
            bool aFirst = (ka > kb) || (ka == kb && ia < ib);
            bool desc = ((i & size) == 0);
            if (desc ? !aFirst : aFirst) {
                sk[i] = kb; sk[j] = ka; si[i] = ib; si[j] = ia;
            }
            __syncthreads();
        }
    }

    for (int j = t; j < NPROP; j += 512) {
        sortedS[(size_t)c * NPROP + j] = sk[j];
        const float4 bb = *(const float4*)&boxesT[(size_t)(c * NPROP + si[j]) * 4];
        *(float4*)&sortedB[(size_t)(c * NPROP + j) * 4] = bb;
    }
}

// ---------------------------------------------------------------------------
// Greedy NMS per class. One block (256 thr) per class, everything in LDS.
// Writes masked flat scores: keep ? s : -1.
// ---------------------------------------------------------------------------
__global__ __launch_bounds__(256) void nms_k(
    const float* __restrict__ sortedS, const float* __restrict__ sortedB,
    float* __restrict__ sflat)
{
    int c = blockIdx.x, t = threadIdx.x;
    __shared__ float x1s[NPROP], y1s[NPROP], x2s[NPROP], y2s[NPROP], ar[NPROP];
    __shared__ unsigned char kp[NPROP];

    for (int j = t; j < NPROP; j += 256) {
        float4 b = *(const float4*)&sortedB[(size_t)(c * NPROP + j) * 4];
        x1s[j] = b.x; y1s[j] = b.y; x2s[j] = b.z; y2s[j] = b.w;
        ar[j] = fmaxf(b.z - b.x, 0.f) * fmaxf(b.w - b.y, 0.f);
        kp[j] = sortedS[(size_t)c * NPROP + j] > 0.05f;
    }
    __syncthreads();

    for (int i = 0; i < NPROP - 1; i++) {
        if (kp[i]) {                       // wave-uniform LDS read
            float xi1 = x1s[i], yi1 = y1s[i], xi2 = x2s[i], yi2 = y2s[i], ai = ar[i];
            for (int j = i + 1 + t; j < NPROP; j += 256) {
                float iw = fmaxf(fminf(xi2, x2s[j]) - fmaxf(xi1, x1s[j]), 0.f);
                float ih = fmaxf(fminf(yi2, y2s[j]) - fmaxf(yi1, y1s[j]), 0.f);
                float inter = iw * ih;
                float iou = inter / fmaxf(ai + ar[j] - inter, 1e-8f);
                if (iou > 0.5f) kp[j] = 0;
            }
        }
        __syncthreads();
    }

    for (int j = t; j < NPROP; j += 256) {
        sflat[(size_t)c * NPROP + j] = kp[j] ? sortedS[(size_t)c * NPROP + j] : -1.0f;
    }
}

// ---------------------------------------------------------------------------
// Global top-100 (value desc, index asc tie-break, matches lax.top_k) + output.
// Single block, 1024 threads, iterative argmax.
// ---------------------------------------------------------------------------
__global__ __launch_bounds__(1024) void topk_k(
    float* __restrict__ sflat, const float* __restrict__ sortedB,
    float* __restrict__ out)
{
    int t = threadIdx.x;
    __shared__ float rv[1024];
    __shared__ int   ri[1024];
    __shared__ float topv[100];
    __shared__ int   topi[100];

    for (int r = 0; r < 100; r++) {
        float bv = -2e30f; int bi = 0x7fffffff;
        for (int idx = t; idx < NCLS * NPROP; idx += 1024) {
            float v = sflat[idx];
            if (v > bv) { bv = v; bi = idx; }   // strided asc -> lowest idx on tie
        }
        rv[t] = bv; ri[t] = bi;
        __syncthreads();
        for (int s = 512; s > 0; s >>= 1) {
            if (t < s) {
                float ov = rv[t + s]; int oi = ri[t + s];
                if (ov > rv[t] || (ov == rv[t] && oi < ri[t])) { rv[t] = ov; ri[t] = oi; }
            }
            __syncthreads();
        }
        if (t == 0) { topv[r] = rv[0]; topi[r] = ri[0]; sflat[ri[0]] = -2e30f; }
        __syncthreads();
    }

    if (t < 100) {
        float v = topv[t]; int fi = topi[t];
        bool valid = v > 0.0f;
        float4 bb = make_float4(0.f, 0.f, 0.f, 0.f);
        if (valid) bb = *(const float4*)&sortedB[(size_t)fi * 4];
        out[1 + t * 4 + 0] = bb.x;
        out[1 + t * 4 + 1] = bb.y;
        out[1 + t * 4 + 2] = bb.z;
        out[1 + t * 4 + 3] = bb.w;
        out[401 + t] = valid ? v : 0.0f;
        out[501 + t] = valid ? (float)(fi / NPROP) : -1.0f;
    }
    if (t == 0) {
        int n = 0;
        for (int r = 0; r < 100; r++) n += (topv[r] > 0.0f) ? 1 : 0;
        out[0] = (float)n;
    }
}

// ---------------------------------------------------------------------------
extern "C" void kernel_launch(void* const* d_in, const int* in_sizes, int n_in,
                              void* d_out, int out_size, void* d_ws, size_t ws_size,
                              hipStream_t stream)
{
    const float* f0    = (const float*)d_in[0];
    const float* f1    = (const float*)d_in[1];
    const float* f2    = (const float*)d_in[2];
    const float* f3    = (const float*)d_in[3];
    const float* props = (const float*)d_in[4];
    const float* fc1_w = (const float*)d_in[5];
    const float* fc1_b = (const float*)d_in[6];
    const float* fc2_w = (const float*)d_in[7];
    const float* fc2_b = (const float*)d_in[8];
    const float* cls_w = (const float*)d_in[9];
    const float* cls_b = (const float*)d_in[10];
    const float* reg_w = (const float*)d_in[11];
    const float* reg_b = (const float*)d_in[12];
    float* out = (float*)d_out;

    float* ws = (float*)d_ws;
    size_t off = 0;
    float* h1      = ws + off; off += (size_t)NPROP * FCDIM;   // 1,024,000
    float* h2      = ws + off; off += (size_t)NPROP * FCDIM;   // 1,024,000
    float* cls_s   = ws + off; off += (size_t)NPROP * 81;      //    81,000
    float* reg_s   = ws + off; off += (size_t)NPROP * 320;     //   320,000
    float* probsT  = ws + off; off += (size_t)NCLS * NPROP;    //    80,000
    float* boxesT  = ws + off; off += (size_t)NCLS * NPROP * 4;//   320,000
    float* sortedS = ws + off; off += (size_t)NCLS * NPROP;    //    80,000
    float* sortedB = ws + off; off += (size_t)NCLS * NPROP * 4;//   320,000
    float* sflat   = ws + off; off += (size_t)NCLS * NPROP;    //    80,000
    float* roiBuf  = ws + off;

    size_t availF = (ws_size / 4 > off) ? (ws_size / 4 - off) : 0;
    int CH = (int)((availF / DFLAT < (size_t)NPROP) ? (availF / DFLAT) : (size_t)NPROP);
    if (CH < 1) CH = 1;   // assume ws_size is at least ~14 MB

    for (int s = 0; s < NPROP; s += CH) {
        int cur = (NPROP - s < CH) ? (NPROP - s) : CH;
        roi_align_k<<<cur, 256, 0, stream>>>(f0, f1, f2, f3, props, roiBuf, s);
        dim3 g1(FCDIM / 64, (cur + 63) / 64);
        gemm_tn_k<<<g1, 256, 0, stream>>>(roiBuf, fc1_w, fc1_b,
                                          h1 + (size_t)s * FCDIM,
                                          cur, FCDIM, DFLAT, 1);
    }

    gemm_tn_k<<<dim3(FCDIM / 64, (NPROP + 63) / 64), 256, 0, stream>>>(
        h1, fc2_w, fc2_b, h2, NPROP, FCDIM, FCDIM, 1);
    gemm_tn_k<<<dim3((81 + 63) / 64, (NPROP + 63) / 64), 256, 0, stream>>>(
        h2, cls_w, cls_b, cls_s, NPROP, 81, FCDIM, 0);
    gemm_tn_k<<<dim3((320 + 63) / 64, (NPROP + 63) / 64), 256, 0, stream>>>(
        h2, reg_w, reg_b, reg_s, NPROP, 320, FCDIM, 0);

    head_post_k<<<NPROP, 128, 0, stream>>>(cls_s, reg_s, props, probsT, boxesT);
    sort_k<<<NCLS, 512, 0, stream>>>(probsT, boxesT, sortedS, sortedB);
    nms_k<<<NCLS, 256, 0, stream>>>(sortedS, sortedB, sflat);
    topk_k<<<1, 1024, 0, stream>>>(sflat, sortedB, out);
}

// Round 2
// 1899.701 us; speedup vs baseline: 1.8872x; 1.8872x over previous
//
#include <hip/hip_runtime.h>
#include <math.h>

#define NCLS   80
#define NPROP  1000
#define FCDIM  1024
#define DFLAT  12544   // 256*7*7
#define MPAD   1024
#define MAXR   4.1351665567423560f

typedef unsigned short ushort_t;
using short8  = __attribute__((ext_vector_type(8))) short;
using float4v = __attribute__((ext_vector_type(4))) float;

__device__ inline ushort_t f2bf(float f) {
    unsigned int u = __float_as_uint(f);
    unsigned int r = (u + 0x7fffu + ((u >> 16) & 1u)) >> 16;
    return (ushort_t)r;
}

// ---------------------------------------------------------------------------
// fp32 -> bf16 cast, vectorized x4.
// ---------------------------------------------------------------------------
__global__ __launch_bounds__(256) void cast_bf16_k(
    const float* __restrict__ src, ushort_t* __restrict__ dst, int n4)
{
    int i = blockIdx.x * 256 + threadIdx.x;
    if (i < n4) {
        float4 v = ((const float4*)src)[i];
        ushort4 o;
        o.x = f2bf(v.x); o.y = f2bf(v.y); o.z = f2bf(v.z); o.w = f2bf(v.w);
        ((ushort4*)dst)[i] = o;
    }
}

// ---------------------------------------------------------------------------
// RoI Align, coalescing-friendly: lane = sample point (49 bins x 4 subsamples
// = 196 lanes), loop over 256 channels. Quad shuffle-reduce -> bf16 out.
// Grid 1024: rows >= NPROP are zero pad for the MFMA GEMM.
// ---------------------------------------------------------------------------
__global__ __launch_bounds__(256) void roi_align_k(
    const float* __restrict__ f0, const float* __restrict__ f1,
    const float* __restrict__ f2, const float* __restrict__ f3,
    const float* __restrict__ props, ushort_t* __restrict__ Abf)
{
    int r = blockIdx.x;
    int t = threadIdx.x;

    if (r >= NPROP) {                          // zero pad rows
        for (int i = t; i < DFLAT; i += 256)
            Abf[(size_t)r * DFLAT + i] = 0;
        return;
    }

    const float4 p = *(const float4*)&props[(size_t)r * 4];
    float wp = p.z - p.x, hp = p.w - p.y;
    float scale = sqrtf(fmaxf(wp * hp, 1e-6f));
    int lvl = (int)floorf(log2f(scale / 56.0f + 1e-6f));
    lvl = min(max(lvl, 0), 3);

    const float* f; int H, W; float sc;
    switch (lvl) {
        case 0:  f = f0; H = 200; W = 336; sc = 0.25f;    break;
        case 1:  f = f1; H = 100; W = 168; sc = 0.125f;   break;
        case 2:  f = f2; H = 50;  W = 84;  sc = 0.0625f;  break;
        default: f = f3; H = 25;  W = 42;  sc = 0.03125f; break;
    }

    if (t >= 196) return;

    int b   = t >> 2;          // bin 0..48
    int sub = t & 3;
    int by = b / 7, bx = b - by * 7;
    int sy = by * 2 + (sub >> 1);
    int sx = bx * 2 + (sub & 1);

    float startx = p.x * sc - 0.5f, rangex = (p.z - p.x) * sc;
    float starty = p.y * sc - 0.5f, rangey = (p.w - p.y) * sc;
    float posx = startx + (((float)sx + 0.5f) / 14.0f) * rangex;
    float posy = starty + (((float)sy + 0.5f) / 14.0f) * rangey;

    float flx = floorf(posx), fly = floorf(posy);
    float lx = posx - flx, ly = posy - fly;
    int x0 = min(max((int)flx, 0), W - 1);
    int x1 = min(x0 + 1, W - 1);
    int y0 = min(max((int)fly, 0), H - 1);
    int y1 = min(y0 + 1, H - 1);
    bool valid = (posx >= -1.0f) && (posx <= (float)W) &&
                 (posy >= -1.0f) && (posy <= (float)H);
    float vm = valid ? 0.25f : 0.0f;           // fold sample-avg 1/4 in

    float w00 = (1.f - ly) * (1.f - lx) * vm;
    float w01 = (1.f - ly) * lx * vm;
    float w10 = ly * (1.f - lx) * vm;
    float w11 = ly * lx * vm;
    int o00 = y0 * W + x0, o01 = y0 * W + x1;
    int o10 = y1 * W + x0, o11 = y1 * W + x1;

    ushort_t* orow = Abf + (size_t)r * DFLAT;
    const int HW = H * W;
    const float* pl = f;

    #pragma unroll 4
    for (int c = 0; c < 256; c++) {
        float v = pl[o00] * w00 + pl[o01] * w01 + pl[o10] * w10 + pl[o11] * w11;
        v += __shfl_xor(v, 1);
        v += __shfl_xor(v, 2);
        if (sub == 0)
            orow[c * 49 + b] = f2bf(v);
        pl += HW;
    }
}

// ---------------------------------------------------------------------------
// bf16 MFMA GEMM: C(MxN) = A(MxK) * W(NxK)^T + bias, optional ReLU.
// 128x128 tile, BK=32, 4 waves in 2x2, each wave 4x4 of 16x16x32 MFMA.
// M, N multiples of 128; K multiple of 32. out_bf16: write bf16 else fp32.
// ---------------------------------------------------------------------------
__global__ __launch_bounds__(256) void gemm_bf16_k(
    const ushort_t* __restrict__ A, const ushort_t* __restrict__ W,
    const float* __restrict__ bias, void* __restrict__ Cout,
    int N, int K, int relu, int out_bf16)
{
    __shared__ ushort_t As[128 * 32];
    __shared__ ushort_t Bs[128 * 32];

    int tid = threadIdx.x;
    int w = tid >> 6, l = tid & 63;
    int wm = (w >> 1) * 64, wn = (w & 1) * 64;
    int m0 = blockIdx.y * 128, n0 = blockIdx.x * 128;

    int lrow = tid >> 2;            // 0..63
    int lko  = (tid & 3) * 8;       // 0,8,16,24

    const ushort_t* Ag = A + (size_t)(m0 + lrow) * K + lko;
    const ushort_t* Wg = W + (size_t)(n0 + lrow) * K + lko;
    size_t rowK64 = (size_t)64 * K;

    float4v acc[4][4];
    #pragma unroll
    for (int i = 0; i < 4; i++)
        #pragma unroll
        for (int j = 0; j < 4; j++)
            acc[i][j] = (float4v){0.f, 0.f, 0.f, 0.f};

    int rl = l & 15, q = l >> 4;

    for (int k0 = 0; k0 < K; k0 += 32) {
        uint4 a0 = *(const uint4*)(Ag + k0);
        uint4 a1 = *(const uint4*)(Ag + rowK64 + k0);
        uint4 b0 = *(const uint4*)(Wg + k0);
        uint4 b1 = *(const uint4*)(Wg + rowK64 + k0);
        *(uint4*)&As[lrow * 32 + lko]        = a0;
        *(uint4*)&As[(lrow + 64) * 32 + lko] = a1;
        *(uint4*)&Bs[lrow * 32 + lko]        = b0;
        *(uint4*)&Bs[(lrow + 64) * 32 + lko] = b1;
        __syncthreads();

        short8 af[4], bfr[4];
        #pragma unroll
        for (int i = 0; i < 4; i++)
            af[i] = *(const short8*)&As[(wm + i * 16 + rl) * 32 + q * 8];
        #pragma unroll
        for (int j = 0; j < 4; j++)
            bfr[j] = *(const short8*)&Bs[(wn + j * 16 + rl) * 32 + q * 8];

        #pragma unroll
        for (int i = 0; i < 4; i++)
            #pragma unroll
            for (int j = 0; j < 4; j++)
                acc[i][j] = __builtin_amdgcn_mfma_f32_16x16x32_bf16(
                    af[i], bfr[j], acc[i][j], 0, 0, 0);
        __syncthreads();
    }

    #pragma unroll
    for (int i = 0; i < 4; i++) {
        #pragma unroll
        for (int j = 0; j < 4; j++) {
            int col = n0 + wn + j * 16 + rl;
            float bs = bias[col];
            #pragma unroll
            for (int rr = 0; rr < 4; rr++) {
                int row = m0 + wm + i * 16 + q * 4 + rr;
                float v = acc[i][j][rr] + bs;
                if (relu) v = fmaxf(v, 0.f);
                if (out_bf16)
                    ((ushort_t*)Cout)[(size_t)row * N + col] = f2bf(v);
                else
                    ((float*)Cout)[(size_t)row * N + col] = v;
            }
        }
    }
}

// ---------------------------------------------------------------------------
// fp32 GEMM (cls/reg heads): C(MxN) = A(MxK) * W(NxK)^T + bias.
// ---------------------------------------------------------------------------
__global__ __launch_bounds__(256) void gemm_tn_k(
    const float* __restrict__ A, const float* __restrict__ W,
    const float* __restrict__ bias, float* __restrict__ C,
    int M, int N, int K, int relu)
{
    __shared__ float As[16][64];
    __shared__ float Bs[16][64];

    int tid = threadIdx.x;
    int tx = tid & 15;
    int ty = tid >> 4;
    int m0 = blockIdx.y * 64, n0 = blockIdx.x * 64;

    int lr = tid >> 2;
    int lk = (tid & 3) << 2;

    const float* Arow = A + (size_t)(m0 + lr) * K + lk;
    const float* Wrow = W + (size_t)(n0 + lr) * K + lk;
    bool mOK = (m0 + lr) < M;
    bool nOK = (n0 + lr) < N;

    float acc[4][4] = {};

    for (int k0 = 0; k0 < K; k0 += 16) {
        float4 av = mOK ? *(const float4*)(Arow + k0) : make_float4(0.f, 0.f, 0.f, 0.f);
        float4 wv = nOK ? *(const float4*)(Wrow + k0) : make_float4(0.f, 0.f, 0.f, 0.f);
        As[lk + 0][lr] = av.x; As[lk + 1][lr] = av.y;
        As[lk + 2][lr] = av.z; As[lk + 3][lr] = av.w;
        Bs[lk + 0][lr] = wv.x; Bs[lk + 1][lr] = wv.y;
        Bs[lk + 2][lr] = wv.z; Bs[lk + 3][lr] = wv.w;
        __syncthreads();

        #pragma unroll
        for (int kk = 0; kk < 16; kk++) {
            float4 a = *(const float4*)&As[kk][ty << 2];
            float4 b = *(const float4*)&Bs[kk][tx << 2];
            acc[0][0] += a.x * b.x; acc[0][1] += a.x * b.y;
            acc[0][2] += a.x * b.z; acc[0][3] += a.x * b.w;
            acc[1][0] += a.y * b.x; acc[1][1] += a.y * b.y;
            acc[1][2] += a.y * b.z; acc[1][3] += a.y * b.w;
            acc[2][0] += a.z * b.x; acc[2][1] += a.z * b.y;
            acc[2][2] += a.z * b.z; acc[2][3] += a.z * b.w;
            acc[3][0] += a.w * b.x; acc[3][1] += a.w * b.y;
            acc[3][2] += a.w * b.z; acc[3][3] += a.w * b.w;
        }
        __syncthreads();
    }

    #pragma unroll
    for (int i = 0; i < 4; i++) {
        int m = m0 + (ty << 2) + i;
        if (m >= M) continue;
        #pragma unroll
        for (int j = 0; j < 4; j++) {
            int n = n0 + (tx << 2) + j;
            if (n < N) {
                float v = acc[i][j] + bias[n];
                if (relu) v = fmaxf(v, 0.f);
                C[(size_t)m * N + n] = v;
            }
        }
    }
}

// ---------------------------------------------------------------------------
// Softmax over 81 classes + delta2bbox. One block per RoI.
// ---------------------------------------------------------------------------
__global__ __launch_bounds__(128) void head_post_k(
    const float* __restrict__ cls_s, const float* __restrict__ reg_s,
    const float* __restrict__ props,
    float* __restrict__ probsT, float* __restrict__ boxesT)
{
    int r = blockIdx.x, t = threadIdx.x;
    __shared__ float red[128];

    float x = (t < 81) ? cls_s[(size_t)r * 81 + t] : -1e30f;
    red[t] = x; __syncthreads();
    for (int s = 64; s > 0; s >>= 1) {
        if (t < s) red[t] = fmaxf(red[t], red[t + s]);
        __syncthreads();
    }
    float mx = red[0];
    __syncthreads();

    float e = (t < 81) ? expf(x - mx) : 0.f;
    red[t] = e; __syncthreads();
    for (int s = 64; s > 0; s >>= 1) {
        if (t < s) red[t] += red[t + s];
        __syncthreads();
    }
    float inv = 1.f / red[0];

    if (t < NCLS) {
        probsT[(size_t)t * NPROP + r] = e * inv;

        const float4 p = *(const float4*)&props[(size_t)r * 4];
        float4 d = *(const float4*)&reg_s[(size_t)r * 320 + t * 4];
        float dx = d.x * 0.1f, dy = d.y * 0.1f;
        float dw = fminf(fmaxf(d.z * 0.2f, -MAXR), MAXR);
        float dh = fminf(fmaxf(d.w * 0.2f, -MAXR), MAXR);
        float px = (p.x + p.z) * 0.5f, py = (p.y + p.w) * 0.5f;
        float pw = p.z - p.x, ph = p.w - p.y;
        float gw = pw * expf(dw), gh = ph * expf(dh);
        float gx = px + pw * dx, gy = py + ph * dy;
        float4 bo = make_float4(gx - gw * 0.5f, gy - gh * 0.5f,
                                gx + gw * 0.5f, gy + gh * 0.5f);
        *(float4*)&boxesT[(size_t)(t * NPROP + r) * 4] = bo;
    }
}

// ---------------------------------------------------------------------------
// Per-class stable descending bitonic sort on (score desc, idx asc).
// ---------------------------------------------------------------------------
__global__ __launch_bounds__(512) void sort_k(
    const float* __restrict__ probsT, const float* __restrict__ boxesT,
    float* __restrict__ sortedS, float* __restrict__ sortedB)
{
    int c = blockIdx.x, t = threadIdx.x;
    __shared__ float sk[1024];
    __shared__ int   si[1024];

    for (int j = t; j < 1024; j += 512) {
        sk[j] = (j < NPROP) ? probsT[(size_t)c * NPROP + j] : -1e30f;
        si[j] = j;
    }
    __syncthreads();

    for (int size = 2; size <= 1024; size <<= 1) {
        for (int stride = size >> 1; stride > 0; stride >>= 1) {
            int i = (t << 1) - (t & (stride - 1));
            int j = i + stride;
            float ka = sk[i], kb = sk[j];
            int ia = si[i], ib = si[j];
            bool aFirst = (ka > kb) || (ka == kb && ia < ib);
            bool desc = ((i & size) == 0);
            if (desc ? !aFirst : aFirst) {
                sk[i] = kb; sk[j] = ka; si[i] = ib; si[j] = ia;
            }
            __syncthreads();
        }
    }

    for (int j = t; j < NPROP; j += 512) {
        sortedS[(size_t)c * NPROP + j] = sk[j];
        const float4 bb = *(const float4*)&boxesT[(size_t)(c * NPROP + si[j]) * 4];
        *(float4*)&sortedB[(size_t)(c * NPROP + j) * 4] = bb;
    }
}

// ---------------------------------------------------------------------------
// Greedy NMS per class, in LDS.
// ---------------------------------------------------------------------------
__global__ __launch_bounds__(256) void nms_k(
    const float* __restrict__ sortedS, const float* __restrict__ sortedB,
    float* __restrict__ sflat)
{
    int c = blockIdx.x, t = threadIdx.x;
    __shared__ float x1s[NPROP], y1s[NPROP], x2s[NPROP], y2s[NPROP], ar[NPROP];
    __shared__ unsigned char kp[NPROP];

    for (int j = t; j < NPROP; j += 256) {
        float4 b = *(const float4*)&sortedB[(size_t)(c * NPROP + j) * 4];
        x1s[j] = b.x; y1s[j] = b.y; x2s[j] = b.z; y2s[j] = b.w;
        ar[j] = fmaxf(b.z - b.x, 0.f) * fmaxf(b.w - b.y, 0.f);
        kp[j] = sortedS[(size_t)c * NPROP + j] > 0.05f;
    }
    __syncthreads();

    for (int i = 0; i < NPROP - 1; i++) {
        if (kp[i]) {
            float xi1 = x1s[i], yi1 = y1s[i], xi2 = x2s[i], yi2 = y2s[i], ai = ar[i];
            for (int j = i + 1 + t; j < NPROP; j += 256) {
                float iw = fmaxf(fminf(xi2, x2s[j]) - fmaxf(xi1, x1s[j]), 0.f);
                float ih = fmaxf(fminf(yi2, y2s[j]) - fmaxf(yi1, y1s[j]), 0.f);
                float inter = iw * ih;
                float iou = inter / fmaxf(ai + ar[j] - inter, 1e-8f);
                if (iou > 0.5f) kp[j] = 0;
            }
        }
        __syncthreads();
    }

    for (int j = t; j < NPROP; j += 256) {
        sflat[(size_t)c * NPROP + j] = kp[j] ? sortedS[(size_t)c * NPROP + j] : -1.0f;
    }
}

// ---------------------------------------------------------------------------
// Global top-100 (value desc, index asc tie-break) + final output.
// ---------------------------------------------------------------------------
__global__ __launch_bounds__(1024) void topk_k(
    float* __restrict__ sflat, const float* __restrict__ sortedB,
    float* __restrict__ out)
{
    int t = threadIdx.x;
    __shared__ float rv[1024];
    __shared__ int   ri[1024];
    __shared__ float topv[100];
    __shared__ int   topi[100];

    for (int r = 0; r < 100; r++) {
        float bv = -2e30f; int bi = 0x7fffffff;
        for (int idx = t; idx < NCLS * NPROP; idx += 1024) {
            float v = sflat[idx];
            if (v > bv) { bv = v; bi = idx; }
        }
        rv[t] = bv; ri[t] = bi;
        __syncthreads();
        for (int s = 512; s > 0; s >>= 1) {
            if (t < s) {
                float ov = rv[t + s]; int oi = ri[t + s];
                if (ov > rv[t] || (ov == rv[t] && oi < ri[t])) { rv[t] = ov; ri[t] = oi; }
            }
            __syncthreads();
        }
        if (t == 0) { topv[r] = rv[0]; topi[r] = ri[0]; sflat[ri[0]] = -2e30f; }
        __syncthreads();
    }

    if (t < 100) {
        float v = topv[t]; int fi = topi[t];
        bool valid = v > 0.0f;
        float4 bb = make_float4(0.f, 0.f, 0.f, 0.f);
        if (valid) bb = *(const float4*)&sortedB[(size_t)fi * 4];
        out[1 + t * 4 + 0] = bb.x;
        out[1 + t * 4 + 1] = bb.y;
        out[1 + t * 4 + 2] = bb.z;
        out[1 + t * 4 + 3] = bb.w;
        out[401 + t] = valid ? v : 0.0f;
        out[501 + t] = valid ? (float)(fi / NPROP) : -1.0f;
    }
    if (t == 0) {
        int n = 0;
        for (int r = 0; r < 100; r++) n += (topv[r] > 0.0f) ? 1 : 0;
        out[0] = (float)n;
    }
}

// ---------------------------------------------------------------------------
extern "C" void kernel_launch(void* const* d_in, const int* in_sizes, int n_in,
                              void* d_out, int out_size, void* d_ws, size_t ws_size,
                              hipStream_t stream)
{
    const float* f0    = (const float*)d_in[0];
    const float* f1    = (const float*)d_in[1];
    const float* f2    = (const float*)d_in[2];
    const float* f3    = (const float*)d_in[3];
    const float* props = (const float*)d_in[4];
    const float* fc1_w = (const float*)d_in[5];
    const float* fc1_b = (const float*)d_in[6];
    const float* fc2_w = (const float*)d_in[7];
    const float* fc2_b = (const float*)d_in[8];
    const float* cls_w = (const float*)d_in[9];
    const float* cls_b = (const float*)d_in[10];
    const float* reg_w = (const float*)d_in[11];
    const float* reg_b = (const float*)d_in[12];
    float* out = (float*)d_out;

    // --- workspace carve (all 256B-aligned; total 63,288,832 B) ---
    unsigned char* base = (unsigned char*)d_ws;
    ushort_t* w1bf   = (ushort_t*)(base);              // 25,690,112
    ushort_t* w2bf   = (ushort_t*)(base + 25690112);   //  2,097,152
    ushort_t* Abf    = (ushort_t*)(base + 27787264);   // 25,690,112
    ushort_t* h1     = (ushort_t*)(base + 53477376);   //  2,097,152
    float*    h2     = (float*)(base + 55574528);      //  4,194,304
    float*    probsT = (float*)(base + 59768832);      //    320,000
    float*    boxesT = (float*)(base + 60088832);      //  1,280,000
    float*    sortedS= (float*)(base + 61368832);      //    320,000
    float*    sortedB= (float*)(base + 61688832);      //  1,280,000
    float*    sflat  = (float*)(base + 62968832);      //    320,000
    // aliases: Abf is dead after fc1; cls/reg scores live there afterwards
    float*    cls_s  = (float*)Abf;                    //    324,000
    float*    reg_s  = (float*)(base + 27787264 + 324000); // 1,280,000

    // 1) cast weights to bf16
    cast_bf16_k<<<(FCDIM * DFLAT / 4 + 255) / 256, 256, 0, stream>>>(fc1_w, w1bf, FCDIM * DFLAT / 4);
    cast_bf16_k<<<(FCDIM * FCDIM / 4 + 255) / 256, 256, 0, stream>>>(fc2_w, w2bf, FCDIM * FCDIM / 4);

    // 2) RoI align -> bf16 A matrix (1024 x 12544, pad rows zeroed)
    roi_align_k<<<MPAD, 256, 0, stream>>>(f0, f1, f2, f3, props, Abf);

    // 3) fc1: (1024 x 12544) x (1024 x 12544)^T -> relu -> bf16
    gemm_bf16_k<<<dim3(FCDIM / 128, MPAD / 128), 256, 0, stream>>>(
        Abf, w1bf, fc1_b, h1, FCDIM, DFLAT, 1, 1);

    // 4) fc2: (1024 x 1024) x (1024 x 1024)^T -> relu -> fp32
    gemm_bf16_k<<<dim3(FCDIM / 128, MPAD / 128), 256, 0, stream>>>(
        h1, w2bf, fc2_b, h2, FCDIM, FCDIM, 1, 0);

    // 5) heads (fp32)
    gemm_tn_k<<<dim3((81 + 63) / 64, (NPROP + 63) / 64), 256, 0, stream>>>(
        h2, cls_w, cls_b, cls_s, NPROP, 81, FCDIM, 0);
    gemm_tn_k<<<dim3((320 + 63) / 64, (NPROP + 63) / 64), 256, 0, stream>>>(
        h2, reg_w, reg_b, reg_s, NPROP, 320, FCDIM, 0);

    // 6) post-processing
    head_post_k<<<NPROP, 128, 0, stream>>>(cls_s, reg_s, props, probsT, boxesT);
    sort_k<<<NCLS, 512, 0, stream>>>(probsT, boxesT, sortedS, sortedB);
    nms_k<<<NCLS, 256, 0, stream>>>(sortedS, sortedB, sflat);
    topk_k<<<1, 1024, 0, stream>>>(sflat, sortedB, out);
}

// Round 4
// 957.429 us; speedup vs baseline: 3.7446x; 1.9842x over previous
//
#include <hip/hip_runtime.h>
#include <math.h>

#define NCLS   80
#define NPROP  1000
#define FCDIM  1024
#define DFLAT  12544   // 256*7*7
#define MPAD   1024
#define MAXR   4.1351665567423560f

typedef unsigned short ushort_t;
using short8  = __attribute__((ext_vector_type(8))) short;
using float4v = __attribute__((ext_vector_type(4))) float;

__device__ inline ushort_t f2bf(float f) {
    unsigned int u = __float_as_uint(f);
    unsigned int r = (u + 0x7fffu + ((u >> 16) & 1u)) >> 16;
    return (ushort_t)r;
}

// ---------------------------------------------------------------------------
// fp32 -> bf16 cast, vectorized x4.
// ---------------------------------------------------------------------------
__global__ __launch_bounds__(256) void cast_bf16_k(
    const float* __restrict__ src, ushort_t* __restrict__ dst, int n4)
{
    int i = blockIdx.x * 256 + threadIdx.x;
    if (i < n4) {
        float4 v = ((const float4*)src)[i];
        ushort4 o;
        o.x = f2bf(v.x); o.y = f2bf(v.y); o.z = f2bf(v.z); o.w = f2bf(v.w);
        ((ushort4*)dst)[i] = o;
    }
}

// ---------------------------------------------------------------------------
// RoI Align: lane = sample point (49 bins x 4 subsamples = 196 lanes),
// loop over 256 channels. Quad shuffle-reduce -> bf16 out.
// ---------------------------------------------------------------------------
__global__ __launch_bounds__(256) void roi_align_k(
    const float* __restrict__ f0, const float* __restrict__ f1,
    const float* __restrict__ f2, const float* __restrict__ f3,
    const float* __restrict__ props, ushort_t* __restrict__ Abf)
{
    int r = blockIdx.x;
    int t = threadIdx.x;

    if (r >= NPROP) {                          // zero pad rows
        for (int i = t; i < DFLAT; i += 256)
            Abf[(size_t)r * DFLAT + i] = 0;
        return;
    }

    const float4 p = *(const float4*)&props[(size_t)r * 4];
    float wp = p.z - p.x, hp = p.w - p.y;
    float scale = sqrtf(fmaxf(wp * hp, 1e-6f));
    int lvl = (int)floorf(log2f(scale / 56.0f + 1e-6f));
    lvl = min(max(lvl, 0), 3);

    const float* f; int H, W; float sc;
    switch (lvl) {
        case 0:  f = f0; H = 200; W = 336; sc = 0.25f;    break;
        case 1:  f = f1; H = 100; W = 168; sc = 0.125f;   break;
        case 2:  f = f2; H = 50;  W = 84;  sc = 0.0625f;  break;
        default: f = f3; H = 25;  W = 42;  sc = 0.03125f; break;
    }

    if (t >= 196) return;

    int b   = t >> 2;          // bin 0..48
    int sub = t & 3;
    int by = b / 7, bx = b - by * 7;
    int sy = by * 2 + (sub >> 1);
    int sx = bx * 2 + (sub & 1);

    float startx = p.x * sc - 0.5f, rangex = (p.z - p.x) * sc;
    float starty = p.y * sc - 0.5f, rangey = (p.w - p.y) * sc;
    float posx = startx + (((float)sx + 0.5f) / 14.0f) * rangex;
    float posy = starty + (((float)sy + 0.5f) / 14.0f) * rangey;

    float flx = floorf(posx), fly = floorf(posy);
    float lx = posx - flx, ly = posy - fly;
    int x0 = min(max((int)flx, 0), W - 1);
    int x1 = min(x0 + 1, W - 1);
    int y0 = min(max((int)fly, 0), H - 1);
    int y1 = min(y0 + 1, H - 1);
    bool valid = (posx >= -1.0f) && (posx <= (float)W) &&
                 (posy >= -1.0f) && (posy <= (float)H);
    float vm = valid ? 0.25f : 0.0f;           // fold sample-avg 1/4 in

    float w00 = (1.f - ly) * (1.f - lx) * vm;
    float w01 = (1.f - ly) * lx * vm;
    float w10 = ly * (1.f - lx) * vm;
    float w11 = ly * lx * vm;
    int o00 = y0 * W + x0, o01 = y0 * W + x1;
    int o10 = y1 * W + x0, o11 = y1 * W + x1;

    ushort_t* orow = Abf + (size_t)r * DFLAT;
    const int HW = H * W;
    const float* pl = f;

    #pragma unroll 4
    for (int c = 0; c < 256; c++) {
        float v = pl[o00] * w00 + pl[o01] * w01 + pl[o10] * w10 + pl[o11] * w11;
        v += __shfl_xor(v, 1);
        v += __shfl_xor(v, 2);
        if (sub == 0)
            orow[c * 49 + b] = f2bf(v);
        pl += HW;
    }
}

// ---------------------------------------------------------------------------
// bf16 MFMA GEMM: C(MxN) = A(MxK) * W(NxK)^T + bias, optional ReLU.
// 128x128 tile, BK=32, 4 waves 2x2, each wave 4x4 of 16x16x32 MFMA.
// ---------------------------------------------------------------------------
__global__ __launch_bounds__(256) void gemm_bf16_k(
    const ushort_t* __restrict__ A, const ushort_t* __restrict__ W,
    const float* __restrict__ bias, void* __restrict__ Cout,
    int N, int K, int relu, int out_bf16)
{
    __shared__ ushort_t As[128 * 32];
    __shared__ ushort_t Bs[128 * 32];

    int tid = threadIdx.x;
    int w = tid >> 6, l = tid & 63;
    int wm = (w >> 1) * 64, wn = (w & 1) * 64;
    int m0 = blockIdx.y * 128, n0 = blockIdx.x * 128;

    int lrow = tid >> 2;            // 0..63
    int lko  = (tid & 3) * 8;       // 0,8,16,24

    const ushort_t* Ag = A + (size_t)(m0 + lrow) * K + lko;
    const ushort_t* Wg = W + (size_t)(n0 + lrow) * K + lko;
    size_t rowK64 = (size_t)64 * K;

    float4v acc[4][4];
    #pragma unroll
    for (int i = 0; i < 4; i++)
        #pragma unroll
        for (int j = 0; j < 4; j++)
            acc[i][j] = (float4v){0.f, 0.f, 0.f, 0.f};

    int rl = l & 15, q = l >> 4;

    for (int k0 = 0; k0 < K; k0 += 32) {
        uint4 a0 = *(const uint4*)(Ag + k0);
        uint4 a1 = *(const uint4*)(Ag + rowK64 + k0);
        uint4 b0 = *(const uint4*)(Wg + k0);
        uint4 b1 = *(const uint4*)(Wg + rowK64 + k0);
        *(uint4*)&As[lrow * 32 + lko]        = a0;
        *(uint4*)&As[(lrow + 64) * 32 + lko] = a1;
        *(uint4*)&Bs[lrow * 32 + lko]        = b0;
        *(uint4*)&Bs[(lrow + 64) * 32 + lko] = b1;
        __syncthreads();

        short8 af[4], bfr[4];
        #pragma unroll
        for (int i = 0; i < 4; i++)
            af[i] = *(const short8*)&As[(wm + i * 16 + rl) * 32 + q * 8];
        #pragma unroll
        for (int j = 0; j < 4; j++)
            bfr[j] = *(const short8*)&Bs[(wn + j * 16 + rl) * 32 + q * 8];

        #pragma unroll
        for (int i = 0; i < 4; i++)
            #pragma unroll
            for (int j = 0; j < 4; j++)
                acc[i][j] = __builtin_amdgcn_mfma_f32_16x16x32_bf16(
                    af[i], bfr[j], acc[i][j], 0, 0, 0);
        __syncthreads();
    }

    #pragma unroll
    for (int i = 0; i < 4; i++) {
        #pragma unroll
        for (int j = 0; j < 4; j++) {
            int col = n0 + wn + j * 16 + rl;
            float bs = bias[col];
            #pragma unroll
            for (int rr = 0; rr < 4; rr++) {
                int row = m0 + wm + i * 16 + q * 4 + rr;
                float v = acc[i][j][rr] + bs;
                if (relu) v = fmaxf(v, 0.f);
                if (out_bf16)
                    ((ushort_t*)Cout)[(size_t)row * N + col] = f2bf(v);
                else
                    ((float*)Cout)[(size_t)row * N + col] = v;
            }
        }
    }
}

// ---------------------------------------------------------------------------
// fp32 GEMM (cls/reg heads).
// ---------------------------------------------------------------------------
__global__ __launch_bounds__(256) void gemm_tn_k(
    const float* __restrict__ A, const float* __restrict__ W,
    const float* __restrict__ bias, float* __restrict__ C,
    int M, int N, int K, int relu)
{
    __shared__ float As[16][64];
    __shared__ float Bs[16][64];

    int tid = threadIdx.x;
    int tx = tid & 15;
    int ty = tid >> 4;
    int m0 = blockIdx.y * 64, n0 = blockIdx.x * 64;

    int lr = tid >> 2;
    int lk = (tid & 3) << 2;

    const float* Arow = A + (size_t)(m0 + lr) * K + lk;
    const float* Wrow = W + (size_t)(n0 + lr) * K + lk;
    bool mOK = (m0 + lr) < M;
    bool nOK = (n0 + lr) < N;

    float acc[4][4] = {};

    for (int k0 = 0; k0 < K; k0 += 16) {
        float4 av = mOK ? *(const float4*)(Arow + k0) : make_float4(0.f, 0.f, 0.f, 0.f);
        float4 wv = nOK ? *(const float4*)(Wrow + k0) : make_float4(0.f, 0.f, 0.f, 0.f);
        As[lk + 0][lr] = av.x; As[lk + 1][lr] = av.y;
        As[lk + 2][lr] = av.z; As[lk + 3][lr] = av.w;
        Bs[lk + 0][lr] = wv.x; Bs[lk + 1][lr] = wv.y;
        Bs[lk + 2][lr] = wv.z; Bs[lk + 3][lr] = wv.w;
        __syncthreads();

        #pragma unroll
        for (int kk = 0; kk < 16; kk++) {
            float4 a = *(const float4*)&As[kk][ty << 2];
            float4 b = *(const float4*)&Bs[kk][tx << 2];
            acc[0][0] += a.x * b.x; acc[0][1] += a.x * b.y;
            acc[0][2] += a.x * b.z; acc[0][3] += a.x * b.w;
            acc[1][0] += a.y * b.x; acc[1][1] += a.y * b.y;
            acc[1][2] += a.y * b.z; acc[1][3] += a.y * b.w;
            acc[2][0] += a.z * b.x; acc[2][1] += a.z * b.y;
            acc[2][2] += a.z * b.z; acc[2][3] += a.z * b.w;
            acc[3][0] += a.w * b.x; acc[3][1] += a.w * b.y;
            acc[3][2] += a.w * b.z; acc[3][3] += a.w * b.w;
        }
        __syncthreads();
    }

    #pragma unroll
    for (int i = 0; i < 4; i++) {
        int m = m0 + (ty << 2) + i;
        if (m >= M) continue;
        #pragma unroll
        for (int j = 0; j < 4; j++) {
            int n = n0 + (tx << 2) + j;
            if (n < N) {
                float v = acc[i][j] + bias[n];
                if (relu) v = fmaxf(v, 0.f);
                C[(size_t)m * N + n] = v;
            }
        }
    }
}

// ---------------------------------------------------------------------------
// Softmax over 81 classes + delta2bbox. One block per RoI.
// ---------------------------------------------------------------------------
__global__ __launch_bounds__(128) void head_post_k(
    const float* __restrict__ cls_s, const float* __restrict__ reg_s,
    const float* __restrict__ props,
    float* __restrict__ probsT, float* __restrict__ boxesT)
{
    int r = blockIdx.x, t = threadIdx.x;
    __shared__ float red[128];

    float x = (t < 81) ? cls_s[(size_t)r * 81 + t] : -1e30f;
    red[t] = x; __syncthreads();
    for (int s = 64; s > 0; s >>= 1) {
        if (t < s) red[t] = fmaxf(red[t], red[t + s]);
        __syncthreads();
    }
    float mx = red[0];
    __syncthreads();

    float e = (t < 81) ? expf(x - mx) : 0.f;
    red[t] = e; __syncthreads();
    for (int s = 64; s > 0; s >>= 1) {
        if (t < s) red[t] += red[t + s];
        __syncthreads();
    }
    float inv = 1.f / red[0];

    if (t < NCLS) {
        probsT[(size_t)t * NPROP + r] = e * inv;

        const float4 p = *(const float4*)&props[(size_t)r * 4];
        float4 d = *(const float4*)&reg_s[(size_t)r * 320 + t * 4];
        float dx = d.x * 0.1f, dy = d.y * 0.1f;
        float dw = fminf(fmaxf(d.z * 0.2f, -MAXR), MAXR);
        float dh = fminf(fmaxf(d.w * 0.2f, -MAXR), MAXR);
        float px = (p.x + p.z) * 0.5f, py = (p.y + p.w) * 0.5f;
        float pw = p.z - p.x, ph = p.w - p.y;
        float gw = pw * expf(dw), gh = ph * expf(dh);
        float gx = px + pw * dx, gy = py + ph * dy;
        float4 bo = make_float4(gx - gw * 0.5f, gy - gh * 0.5f,
                                gx + gw * 0.5f, gy + gh * 0.5f);
        *(float4*)&boxesT[(size_t)(t * NPROP + r) * 4] = bo;
    }
}

// ---------------------------------------------------------------------------
// Per-class stable descending bitonic sort on (score desc, idx asc).
// ---------------------------------------------------------------------------
__global__ __launch_bounds__(512) void sort_k(
    const float* __restrict__ probsT, const float* __restrict__ boxesT,
    float* __restrict__ sortedS, float* __restrict__ sortedB)
{
    int c = blockIdx.x, t = threadIdx.x;
    __shared__ float sk[1024];
    __shared__ int   si[1024];

    for (int j = t; j < 1024; j += 512) {
        sk[j] = (j < NPROP) ? probsT[(size_t)c * NPROP + j] : -1e30f;
        si[j] = j;
    }
    __syncthreads();

    for (int size = 2; size <= 1024; size <<= 1) {
        for (int stride = size >> 1; stride > 0; stride >>= 1) {
            int i = (t << 1) - (t & (stride - 1));
            int j = i + stride;
            float ka = sk[i], kb = sk[j];
            int ia = si[i], ib = si[j];
            bool aFirst = (ka > kb) || (ka == kb && ia < ib);
            bool desc = ((i & size) == 0);
            if (desc ? !aFirst : aFirst) {
                sk[i] = kb; sk[j] = ka; si[i] = ib; si[j] = ia;
            }
            __syncthreads();
        }
    }

    for (int j = t; j < NPROP; j += 512) {
        sortedS[(size_t)c * NPROP + j] = sk[j];
        const float4 bb = *(const float4*)&boxesT[(size_t)(c * NPROP + si[j]) * 4];
        *(float4*)&sortedB[(size_t)(c * NPROP + j) * 4] = bb;
    }
}

// ---------------------------------------------------------------------------
// Greedy NMS per class + stable compaction of first <=100 kept candidates.
// Only the first 100 kept per class can reach the global top-100 (per-class
// scores are descending, so the 101st kept is dominated by 100 same-class
// entries with lower flat index). Compaction preserves (desc score, asc idx)
// order, so candS[c*100..] is a sorted list.
// ---------------------------------------------------------------------------
__global__ __launch_bounds__(256) void nms_k(
    const float* __restrict__ sortedS, const float* __restrict__ sortedB,
    float* __restrict__ candS, int* __restrict__ candI)
{
    int c = blockIdx.x, t = threadIdx.x;
    __shared__ float x1s[NPROP], y1s[NPROP], x2s[NPROP], y2s[NPROP], ar[NPROP];
    __shared__ unsigned char kp[NPROP];
    __shared__ int segc[256];

    for (int j = t; j < NPROP; j += 256) {
        float4 b = *(const float4*)&sortedB[(size_t)(c * NPROP + j) * 4];
        x1s[j] = b.x; y1s[j] = b.y; x2s[j] = b.z; y2s[j] = b.w;
        ar[j] = fmaxf(b.z - b.x, 0.f) * fmaxf(b.w - b.y, 0.f);
        kp[j] = sortedS[(size_t)c * NPROP + j] > 0.05f;
    }
    __syncthreads();

    for (int i = 0; i < NPROP - 1; i++) {
        if (kp[i]) {
            float xi1 = x1s[i], yi1 = y1s[i], xi2 = x2s[i], yi2 = y2s[i], ai = ar[i];
            for (int j = i + 1 + t; j < NPROP; j += 256) {
                float iw = fmaxf(fminf(xi2, x2s[j]) - fmaxf(xi1, x1s[j]), 0.f);
                float ih = fmaxf(fminf(yi2, y2s[j]) - fmaxf(yi1, y1s[j]), 0.f);
                float inter = iw * ih;
                float iou = inter / fmaxf(ai + ar[j] - inter, 1e-8f);
                if (iou > 0.5f) kp[j] = 0;
            }
        }
        __syncthreads();
    }

    // stable compaction: thread t owns contiguous entries [t*4, t*4+4)
    int j0 = t * 4;
    int cnt = 0;
    #pragma unroll
    for (int k = 0; k < 4; k++) {
        int j = j0 + k;
        if (j < NPROP && kp[j]) cnt++;
    }
    segc[t] = cnt;
    __syncthreads();
    for (int off = 1; off < 256; off <<= 1) {
        int add = (t >= off) ? segc[t - off] : 0;
        __syncthreads();
        segc[t] += add;
        __syncthreads();
    }
    int pos = segc[t] - cnt;        // exclusive prefix
    #pragma unroll
    for (int k = 0; k < 4; k++) {
        int j = j0 + k;
        if (j < NPROP && kp[j]) {
            if (pos < 100) {
                candS[c * 100 + pos] = sortedS[(size_t)c * NPROP + j];
                candI[c * 100 + pos] = c * NPROP + j;
            }
            pos++;
        }
    }
    int total = segc[255];
    for (int p = total + t; p < 100; p += 256) {
        candS[c * 100 + p] = -2e30f;
        candI[c * 100 + p] = 0x7fffffff;
    }
}

// ---------------------------------------------------------------------------
// Final top-100 via 80-way merge of the per-class sorted candidate lists.
// 100 rounds of argmax over the 80 heads, tie-break (value desc, idx asc)
// == lax.top_k order. One block, 128 threads, tiny LDS.
// ---------------------------------------------------------------------------
__global__ __launch_bounds__(128) void merge_k(
    const float* __restrict__ candS, const int* __restrict__ candI,
    const float* __restrict__ sortedB, float* __restrict__ out)
{
    int t = threadIdx.x;
    __shared__ int   head[NCLS];
    __shared__ float bv[128];
    __shared__ int   bi[128];
    __shared__ int   bc[128];
    __shared__ float topv[100];
    __shared__ int   topi[100];

    if (t < NCLS) head[t] = 0;
    __syncthreads();

    for (int r = 0; r < 100; r++) {
        float v = -2e30f; int fi = 0x7fffffff;
        if (t < NCLS) {
            int h = head[t];
            if (h < 100) { v = candS[t * 100 + h]; fi = candI[t * 100 + h]; }
        }
        bv[t] = v; bi[t] = fi; bc[t] = t;
        __syncthreads();
        for (int s = 64; s > 0; s >>= 1) {
            if (t < s) {
                float ov = bv[t + s]; int oi = bi[t + s];
                if (ov > bv[t] || (ov == bv[t] && oi < bi[t])) {
                    bv[t] = ov; bi[t] = oi; bc[t] = bc[t + s];
                }
            }
            __syncthreads();
        }
        if (t == 0) {
            topv[r] = bv[0]; topi[r] = bi[0];
            head[bc[0]]++;          // advancing past a sentinel is harmless
        }
        __syncthreads();
    }

    if (t < 100) {
        float v = topv[t]; int fi = topi[t];
        bool valid = v > 0.0f;
        float4 bb = make_float4(0.f, 0.f, 0.f, 0.f);
        if (valid) bb = *(const float4*)&sortedB[(size_t)fi * 4];
        out[1 + t * 4 + 0] = bb.x;
        out[1 + t * 4 + 1] = bb.y;
        out[1 + t * 4 + 2] = bb.z;
        out[1 + t * 4 + 3] = bb.w;
        out[401 + t] = valid ? v : 0.0f;
        out[501 + t] = valid ? (float)(fi / NPROP) : -1.0f;
    }
    if (t == 0) {
        int n = 0;
        for (int r = 0; r < 100; r++) n += (topv[r] > 0.0f) ? 1 : 0;
        out[0] = (float)n;
    }
}

// ---------------------------------------------------------------------------
extern "C" void kernel_launch(void* const* d_in, const int* in_sizes, int n_in,
                              void* d_out, int out_size, void* d_ws, size_t ws_size,
                              hipStream_t stream)
{
    const float* f0    = (const float*)d_in[0];
    const float* f1    = (const float*)d_in[1];
    const float* f2    = (const float*)d_in[2];
    const float* f3    = (const float*)d_in[3];
    const float* props = (const float*)d_in[4];
    const float* fc1_w = (const float*)d_in[5];
    const float* fc1_b = (const float*)d_in[6];
    const float* fc2_w = (const float*)d_in[7];
    const float* fc2_b = (const float*)d_in[8];
    const float* cls_w = (const float*)d_in[9];
    const float* cls_b = (const float*)d_in[10];
    const float* reg_w = (const float*)d_in[11];
    const float* reg_b = (const float*)d_in[12];
    float* out = (float*)d_out;

    // --- workspace carve (total 63,288,832 B, all regions disjoint) ---
    unsigned char* base = (unsigned char*)d_ws;
    ushort_t* w1bf   = (ushort_t*)(base);              // 25,690,112 (dead after fc1)
    ushort_t* w2bf   = (ushort_t*)(base + 25690112);   //  2,097,152
    ushort_t* Abf    = (ushort_t*)(base + 27787264);   // 25,690,112 (dead after fc1)
    ushort_t* h1     = (ushort_t*)(base + 53477376);   //  2,097,152
    float*    h2     = (float*)(base + 55574528);      //  4,194,304
    float*    probsT = (float*)(base + 59768832);      //    320,000
    float*    boxesT = (float*)(base + 60088832);      //  1,280,000
    float*    sortedS= (float*)(base + 61368832);      //    320,000
    float*    sortedB= (float*)(base + 61688832);      //  1,280,000
    float*    candS  = (float*)(base + 62968832);      //     32,000
    int*      candI  = (int*)(base + 63000832);        //     32,000
    // aliases into the dead Abf region (after fc1):
    float*    cls_s  = (float*)Abf;                         //   324,000
    float*    reg_s  = (float*)(base + 27787264 + 324000);  // 1,280,000

    // 1) cast weights to bf16
    cast_bf16_k<<<(FCDIM * DFLAT / 4 + 255) / 256, 256, 0, stream>>>(fc1_w, w1bf, FCDIM * DFLAT / 4);
    cast_bf16_k<<<(FCDIM * FCDIM / 4 + 255) / 256, 256, 0, stream>>>(fc2_w, w2bf, FCDIM * FCDIM / 4);

    // 2) RoI align -> bf16 A matrix (1024 x 12544, pad rows zeroed)
    roi_align_k<<<MPAD, 256, 0, stream>>>(f0, f1, f2, f3, props, Abf);

    // 3) fc1: relu((1024x12544) x (1024x12544)^T) -> bf16
    gemm_bf16_k<<<dim3(FCDIM / 128, MPAD / 128), 256, 0, stream>>>(
        Abf, w1bf, fc1_b, h1, FCDIM, DFLAT, 1, 1);

    // 4) fc2: relu((1024x1024) x (1024x1024)^T) -> fp32
    gemm_bf16_k<<<dim3(FCDIM / 128, MPAD / 128), 256, 0, stream>>>(
        h1, w2bf, fc2_b, h2, FCDIM, FCDIM, 1, 0);

    // 5) heads (fp32)
    gemm_tn_k<<<dim3((81 + 63) / 64, (NPROP + 63) / 64), 256, 0, stream>>>(
        h2, cls_w, cls_b, cls_s, NPROP, 81, FCDIM, 0);
    gemm_tn_k<<<dim3((320 + 63) / 64, (NPROP + 63) / 64), 256, 0, stream>>>(
        h2, reg_w, reg_b, reg_s, NPROP, 320, FCDIM, 0);

    // 6) post-processing
    head_post_k<<<NPROP, 128, 0, stream>>>(cls_s, reg_s, props, probsT, boxesT);
    sort_k<<<NCLS, 512, 0, stream>>>(probsT, boxesT, sortedS, sortedB);
    nms_k<<<NCLS, 256, 0, stream>>>(sortedS, sortedB, candS, candI);
    merge_k<<<1, 128, 0, stream>>>(candS, candI, sortedB, out);
}

// Round 5
// 731.678 us; speedup vs baseline: 4.9000x; 1.3085x over previous
//
#include <hip/hip_runtime.h>
#include <math.h>

#define NCLS   80
#define NPROP  1000
#define FCDIM  1024
#define DFLAT  12544   // 256*7*7
#define MPAD   1024
#define MAXR   4.1351665567423560f
#define LDSP   40      // padded LDS row stride (ushorts): 80B -> 2-way bank alias (free)

typedef unsigned short ushort_t;
using short8  = __attribute__((ext_vector_type(8))) short;
using float4v = __attribute__((ext_vector_type(4))) float;

__device__ inline ushort_t f2bf(float f) {
    unsigned int u = __float_as_uint(f);
    unsigned int r = (u + 0x7fffu + ((u >> 16) & 1u)) >> 16;
    return (ushort_t)r;
}

// ---------------------------------------------------------------------------
// RoI Align: lane = sample point (49 bins x 4 subsamples = 196 lanes),
// loop over 256 channels. Quad shuffle-reduce -> bf16 out.
// ---------------------------------------------------------------------------
__global__ __launch_bounds__(256) void roi_align_k(
    const float* __restrict__ f0, const float* __restrict__ f1,
    const float* __restrict__ f2, const float* __restrict__ f3,
    const float* __restrict__ props, ushort_t* __restrict__ Abf)
{
    int r = blockIdx.x;
    int t = threadIdx.x;

    if (r >= NPROP) {                          // zero pad rows
        for (int i = t; i < DFLAT; i += 256)
            Abf[(size_t)r * DFLAT + i] = 0;
        return;
    }

    const float4 p = *(const float4*)&props[(size_t)r * 4];
    float wp = p.z - p.x, hp = p.w - p.y;
    float scale = sqrtf(fmaxf(wp * hp, 1e-6f));
    int lvl = (int)floorf(log2f(scale / 56.0f + 1e-6f));
    lvl = min(max(lvl, 0), 3);

    const float* f; int H, W; float sc;
    switch (lvl) {
        case 0:  f = f0; H = 200; W = 336; sc = 0.25f;    break;
        case 1:  f = f1; H = 100; W = 168; sc = 0.125f;   break;
        case 2:  f = f2; H = 50;  W = 84;  sc = 0.0625f;  break;
        default: f = f3; H = 25;  W = 42;  sc = 0.03125f; break;
    }

    if (t >= 196) return;

    int b   = t >> 2;          // bin 0..48
    int sub = t & 3;
    int by = b / 7, bx = b - by * 7;
    int sy = by * 2 + (sub >> 1);
    int sx = bx * 2 + (sub & 1);

    float startx = p.x * sc - 0.5f, rangex = (p.z - p.x) * sc;
    float starty = p.y * sc - 0.5f, rangey = (p.w - p.y) * sc;
    float posx = startx + (((float)sx + 0.5f) / 14.0f) * rangex;
    float posy = starty + (((float)sy + 0.5f) / 14.0f) * rangey;

    float flx = floorf(posx), fly = floorf(posy);
    float lx = posx - flx, ly = posy - fly;
    int x0 = min(max((int)flx, 0), W - 1);
    int x1 = min(x0 + 1, W - 1);
    int y0 = min(max((int)fly, 0), H - 1);
    int y1 = min(y0 + 1, H - 1);
    bool valid = (posx >= -1.0f) && (posx <= (float)W) &&
                 (posy >= -1.0f) && (posy <= (float)H);
    float vm = valid ? 0.25f : 0.0f;           // fold sample-avg 1/4 in

    float w00 = (1.f - ly) * (1.f - lx) * vm;
    float w01 = (1.f - ly) * lx * vm;
    float w10 = ly * (1.f - lx) * vm;
    float w11 = ly * lx * vm;
    int o00 = y0 * W + x0, o01 = y0 * W + x1;
    int o10 = y1 * W + x0, o11 = y1 * W + x1;

    ushort_t* orow = Abf + (size_t)r * DFLAT;
    const int HW = H * W;
    const float* pl = f;

    #pragma unroll 4
    for (int c = 0; c < 256; c++) {
        float v = pl[o00] * w00 + pl[o01] * w01 + pl[o10] * w10 + pl[o11] * w11;
        v += __shfl_xor(v, 1);
        v += __shfl_xor(v, 2);
        if (sub == 0)
            orow[c * 49 + b] = f2bf(v);
        pl += HW;
    }
}

// ---------------------------------------------------------------------------
// Split-K bf16 MFMA GEMM: P[z] = A(MPADxK chunk) * W(NxK chunk)^T.
// A is bf16; W is fp32, converted to bf16 in registers during staging.
// 128x128 tile, BK=32, 4 waves 2x2, each wave 4x4 of 16x16x32 MFMA.
// grid (N/128, MPAD/128, SK); block z handles K range [z*KC, (z+1)*KC).
// Partials (no bias/act) go to P + z*MPAD*N, fp32.
// ---------------------------------------------------------------------------
__global__ __launch_bounds__(256) void gemm_sk_k(
    const ushort_t* __restrict__ A, const float* __restrict__ Wf,
    float* __restrict__ P, int N, int K, int KC)
{
    __shared__ ushort_t As[128 * LDSP];
    __shared__ ushort_t Bs[128 * LDSP];

    int tid = threadIdx.x;
    int w = tid >> 6, l = tid & 63;
    int wm = (w >> 1) * 64, wn = (w & 1) * 64;
    int m0 = blockIdx.y * 128, n0 = blockIdx.x * 128;
    int kc0 = blockIdx.z * KC;

    int lrow = tid >> 2;            // 0..63
    int lko  = (tid & 3) * 8;       // 0,8,16,24

    const ushort_t* Ag = A  + (size_t)(m0 + lrow) * K + kc0 + lko;
    const float*    Wg = Wf + (size_t)(n0 + lrow) * K + kc0 + lko;
    size_t rowK64 = (size_t)64 * K;

    float4v acc[4][4];
    #pragma unroll
    for (int i = 0; i < 4; i++)
        #pragma unroll
        for (int j = 0; j < 4; j++)
            acc[i][j] = (float4v){0.f, 0.f, 0.f, 0.f};

    int rl = l & 15, q = l >> 4;

    for (int k0 = 0; k0 < KC; k0 += 32) {
        uint4  a0  = *(const uint4*)(Ag + k0);
        uint4  a1  = *(const uint4*)(Ag + rowK64 + k0);
        float4 w0a = *(const float4*)(Wg + k0);
        float4 w0b = *(const float4*)(Wg + k0 + 4);
        float4 w1a = *(const float4*)(Wg + rowK64 + k0);
        float4 w1b = *(const float4*)(Wg + rowK64 + k0 + 4);

        uint4 wv0, wv1;
        wv0.x = (unsigned)f2bf(w0a.x) | ((unsigned)f2bf(w0a.y) << 16);
        wv0.y = (unsigned)f2bf(w0a.z) | ((unsigned)f2bf(w0a.w) << 16);
        wv0.z = (unsigned)f2bf(w0b.x) | ((unsigned)f2bf(w0b.y) << 16);
        wv0.w = (unsigned)f2bf(w0b.z) | ((unsigned)f2bf(w0b.w) << 16);
        wv1.x = (unsigned)f2bf(w1a.x) | ((unsigned)f2bf(w1a.y) << 16);
        wv1.y = (unsigned)f2bf(w1a.z) | ((unsigned)f2bf(w1a.w) << 16);
        wv1.z = (unsigned)f2bf(w1b.x) | ((unsigned)f2bf(w1b.y) << 16);
        wv1.w = (unsigned)f2bf(w1b.z) | ((unsigned)f2bf(w1b.w) << 16);

        *(uint4*)&As[lrow * LDSP + lko]        = a0;
        *(uint4*)&As[(lrow + 64) * LDSP + lko] = a1;
        *(uint4*)&Bs[lrow * LDSP + lko]        = wv0;
        *(uint4*)&Bs[(lrow + 64) * LDSP + lko] = wv1;
        __syncthreads();

        short8 af[4], bfr[4];
        #pragma unroll
        for (int i = 0; i < 4; i++)
            af[i] = *(const short8*)&As[(wm + i * 16 + rl) * LDSP + q * 8];
        #pragma unroll
        for (int j = 0; j < 4; j++)
            bfr[j] = *(const short8*)&Bs[(wn + j * 16 + rl) * LDSP + q * 8];

        #pragma unroll
        for (int i = 0; i < 4; i++)
            #pragma unroll
            for (int j = 0; j < 4; j++)
                acc[i][j] = __builtin_amdgcn_mfma_f32_16x16x32_bf16(
                    af[i], bfr[j], acc[i][j], 0, 0, 0);
        __syncthreads();
    }

    float* Pz = P + (size_t)blockIdx.z * ((size_t)MPAD * N);
    #pragma unroll
    for (int i = 0; i < 4; i++) {
        #pragma unroll
        for (int j = 0; j < 4; j++) {
            int col = n0 + wn + j * 16 + rl;
            #pragma unroll
            for (int rr = 0; rr < 4; rr++) {
                int row = m0 + wm + i * 16 + q * 4 + rr;
                Pz[(size_t)row * N + col] = acc[i][j][rr];
            }
        }
    }
}

// ---------------------------------------------------------------------------
// Reduce SK partials + bias (+ReLU), write bf16 or fp32.
// grid: MPAD*N/4/256 blocks; N multiple of 4.
// ---------------------------------------------------------------------------
__global__ __launch_bounds__(256) void reduce_sk_k(
    const float* __restrict__ P, const float* __restrict__ bias,
    void* __restrict__ Cout, int N, int SK, int relu, int out_bf16)
{
    size_t idx = ((size_t)blockIdx.x * 256 + threadIdx.x) * 4;
    float4 s = *(const float4*)&P[idx];
    for (int z = 1; z < SK; z++) {
        float4 pv = *(const float4*)&P[(size_t)z * ((size_t)MPAD * N) + idx];
        s.x += pv.x; s.y += pv.y; s.z += pv.z; s.w += pv.w;
    }
    int n = (int)(idx % N);
    float4 b = *(const float4*)&bias[n];
    s.x += b.x; s.y += b.y; s.z += b.z; s.w += b.w;
    if (relu) {
        s.x = fmaxf(s.x, 0.f); s.y = fmaxf(s.y, 0.f);
        s.z = fmaxf(s.z, 0.f); s.w = fmaxf(s.w, 0.f);
    }
    if (out_bf16) {
        ushort4 o;
        o.x = f2bf(s.x); o.y = f2bf(s.y); o.z = f2bf(s.z); o.w = f2bf(s.w);
        *(ushort4*)&((ushort_t*)Cout)[idx] = o;
    } else {
        *(float4*)&((float*)Cout)[idx] = s;
    }
}

// ---------------------------------------------------------------------------
// fp32 GEMM (cls/reg heads).
// ---------------------------------------------------------------------------
__global__ __launch_bounds__(256) void gemm_tn_k(
    const float* __restrict__ A, const float* __restrict__ W,
    const float* __restrict__ bias, float* __restrict__ C,
    int M, int N, int K, int relu)
{
    __shared__ float As[16][64];
    __shared__ float Bs[16][64];

    int tid = threadIdx.x;
    int tx = tid & 15;
    int ty = tid >> 4;
    int m0 = blockIdx.y * 64, n0 = blockIdx.x * 64;

    int lr = tid >> 2;
    int lk = (tid & 3) << 2;

    const float* Arow = A + (size_t)(m0 + lr) * K + lk;
    const float* Wrow = W + (size_t)(n0 + lr) * K + lk;
    bool mOK = (m0 + lr) < M;
    bool nOK = (n0 + lr) < N;

    float acc[4][4] = {};

    for (int k0 = 0; k0 < K; k0 += 16) {
        float4 av = mOK ? *(const float4*)(Arow + k0) : make_float4(0.f, 0.f, 0.f, 0.f);
        float4 wv = nOK ? *(const float4*)(Wrow + k0) : make_float4(0.f, 0.f, 0.f, 0.f);
        As[lk + 0][lr] = av.x; As[lk + 1][lr] = av.y;
        As[lk + 2][lr] = av.z; As[lk + 3][lr] = av.w;
        Bs[lk + 0][lr] = wv.x; Bs[lk + 1][lr] = wv.y;
        Bs[lk + 2][lr] = wv.z; Bs[lk + 3][lr] = wv.w;
        __syncthreads();

        #pragma unroll
        for (int kk = 0; kk < 16; kk++) {
            float4 a = *(const float4*)&As[kk][ty << 2];
            float4 b = *(const float4*)&Bs[kk][tx << 2];
            acc[0][0] += a.x * b.x; acc[0][1] += a.x * b.y;
            acc[0][2] += a.x * b.z; acc[0][3] += a.x * b.w;
            acc[1][0] += a.y * b.x; acc[1][1] += a.y * b.y;
            acc[1][2] += a.y * b.z; acc[1][3] += a.y * b.w;
            acc[2][0] += a.z * b.x; acc[2][1] += a.z * b.y;
            acc[2][2] += a.z * b.z; acc[2][3] += a.z * b.w;
            acc[3][0] += a.w * b.x; acc[3][1] += a.w * b.y;
            acc[3][2] += a.w * b.z; acc[3][3] += a.w * b.w;
        }
        __syncthreads();
    }

    #pragma unroll
    for (int i = 0; i < 4; i++) {
        int m = m0 + (ty << 2) + i;
        if (m >= M) continue;
        #pragma unroll
        for (int j = 0; j < 4; j++) {
            int n = n0 + (tx << 2) + j;
            if (n < N) {
                float v = acc[i][j] + bias[n];
                if (relu) v = fmaxf(v, 0.f);
                C[(size_t)m * N + n] = v;
            }
        }
    }
}

// ---------------------------------------------------------------------------
// Softmax over 81 classes + delta2bbox. One block per RoI.
// ---------------------------------------------------------------------------
__global__ __launch_bounds__(128) void head_post_k(
    const float* __restrict__ cls_s, const float* __restrict__ reg_s,
    const float* __restrict__ props,
    float* __restrict__ probsT, float* __restrict__ boxesT)
{
    int r = blockIdx.x, t = threadIdx.x;
    __shared__ float red[128];

    float x = (t < 81) ? cls_s[(size_t)r * 81 + t] : -1e30f;
    red[t] = x; __syncthreads();
    for (int s = 64; s > 0; s >>= 1) {
        if (t < s) red[t] = fmaxf(red[t], red[t + s]);
        __syncthreads();
    }
    float mx = red[0];
    __syncthreads();

    float e = (t < 81) ? expf(x - mx) : 0.f;
    red[t] = e; __syncthreads();
    for (int s = 64; s > 0; s >>= 1) {
        if (t < s) red[t] += red[t + s];
        __syncthreads();
    }
    float inv = 1.f / red[0];

    if (t < NCLS) {
        probsT[(size_t)t * NPROP + r] = e * inv;

        const float4 p = *(const float4*)&props[(size_t)r * 4];
        float4 d = *(const float4*)&reg_s[(size_t)r * 320 + t * 4];
        float dx = d.x * 0.1f, dy = d.y * 0.1f;
        float dw = fminf(fmaxf(d.z * 0.2f, -MAXR), MAXR);
        float dh = fminf(fmaxf(d.w * 0.2f, -MAXR), MAXR);
        float px = (p.x + p.z) * 0.5f, py = (p.y + p.w) * 0.5f;
        float pw = p.z - p.x, ph = p.w - p.y;
        float gw = pw * expf(dw), gh = ph * expf(dh);
        float gx = px + pw * dx, gy = py + ph * dy;
        float4 bo = make_float4(gx - gw * 0.5f, gy - gh * 0.5f,
                                gx + gw * 0.5f, gy + gh * 0.5f);
        *(float4*)&boxesT[(size_t)(t * NPROP + r) * 4] = bo;
    }
}

// ---------------------------------------------------------------------------
// Per-class stable descending bitonic sort on (score desc, idx asc).
// ---------------------------------------------------------------------------
__global__ __launch_bounds__(512) void sort_k(
    const float* __restrict__ probsT, const float* __restrict__ boxesT,
    float* __restrict__ sortedS, float* __restrict__ sortedB)
{
    int c = blockIdx.x, t = threadIdx.x;
    __shared__ float sk[1024];
    __shared__ int   si[1024];

    for (int j = t; j < 1024; j += 512) {
        sk[j] = (j < NPROP) ? probsT[(size_t)c * NPROP + j] : -1e30f;
        si[j] = j;
    }
    __syncthreads();

    for (int size = 2; size <= 1024; size <<= 1) {
        for (int stride = size >> 1; stride > 0; stride >>= 1) {
            int i = (t << 1) - (t & (stride - 1));
            int j = i + stride;
            float ka = sk[i], kb = sk[j];
            int ia = si[i], ib = si[j];
            bool aFirst = (ka > kb) || (ka == kb && ia < ib);
            bool desc = ((i & size) == 0);
            if (desc ? !aFirst : aFirst) {
                sk[i] = kb; sk[j] = ka; si[i] = ib; si[j] = ia;
            }
            __syncthreads();
        }
    }

    for (int j = t; j < NPROP; j += 512) {
        sortedS[(size_t)c * NPROP + j] = sk[j];
        const float4 bb = *(const float4*)&boxesT[(size_t)(c * NPROP + si[j]) * 4];
        *(float4*)&sortedB[(size_t)(c * NPROP + j) * 4] = bb;
    }
}

// ---------------------------------------------------------------------------
// Greedy NMS per class + stable compaction of first <=100 kept candidates.
// ---------------------------------------------------------------------------
__global__ __launch_bounds__(256) void nms_k(
    const float* __restrict__ sortedS, const float* __restrict__ sortedB,
    float* __restrict__ candS, int* __restrict__ candI)
{
    int c = blockIdx.x, t = threadIdx.x;
    __shared__ float x1s[NPROP], y1s[NPROP], x2s[NPROP], y2s[NPROP], ar[NPROP];
    __shared__ unsigned char kp[NPROP];
    __shared__ int segc[256];

    for (int j = t; j < NPROP; j += 256) {
        float4 b = *(const float4*)&sortedB[(size_t)(c * NPROP + j) * 4];
        x1s[j] = b.x; y1s[j] = b.y; x2s[j] = b.z; y2s[j] = b.w;
        ar[j] = fmaxf(b.z - b.x, 0.f) * fmaxf(b.w - b.y, 0.f);
        kp[j] = sortedS[(size_t)c * NPROP + j] > 0.05f;
    }
    __syncthreads();

    for (int i = 0; i < NPROP - 1; i++) {
        if (kp[i]) {
            float xi1 = x1s[i], yi1 = y1s[i], xi2 = x2s[i], yi2 = y2s[i], ai = ar[i];
            for (int j = i + 1 + t; j < NPROP; j += 256) {
                float iw = fmaxf(fminf(xi2, x2s[j]) - fmaxf(xi1, x1s[j]), 0.f);
                float ih = fmaxf(fminf(yi2, y2s[j]) - fmaxf(yi1, y1s[j]), 0.f);
                float inter = iw * ih;
                float iou = inter / fmaxf(ai + ar[j] - inter, 1e-8f);
                if (iou > 0.5f) kp[j] = 0;
            }
        }
        __syncthreads();
    }

    // stable compaction: thread t owns contiguous entries [t*4, t*4+4)
    int j0 = t * 4;
    int cnt = 0;
    #pragma unroll
    for (int k = 0; k < 4; k++) {
        int j = j0 + k;
        if (j < NPROP && kp[j]) cnt++;
    }
    segc[t] = cnt;
    __syncthreads();
    for (int off = 1; off < 256; off <<= 1) {
        int add = (t >= off) ? segc[t - off] : 0;
        __syncthreads();
        segc[t] += add;
        __syncthreads();
    }
    int pos = segc[t] - cnt;        // exclusive prefix
    #pragma unroll
    for (int k = 0; k < 4; k++) {
        int j = j0 + k;
        if (j < NPROP && kp[j]) {
            if (pos < 100) {
                candS[c * 100 + pos] = sortedS[(size_t)c * NPROP + j];
                candI[c * 100 + pos] = c * NPROP + j;
            }
            pos++;
        }
    }
    int total = segc[255];
    for (int p = total + t; p < 100; p += 256) {
        candS[c * 100 + p] = -2e30f;
        candI[c * 100 + p] = 0x7fffffff;
    }
}

// ---------------------------------------------------------------------------
// Final top-100 via 80-way merge of per-class sorted candidate lists.
// ---------------------------------------------------------------------------
__global__ __launch_bounds__(128) void merge_k(
    const float* __restrict__ candS, const int* __restrict__ candI,
    const float* __restrict__ sortedB, float* __restrict__ out)
{
    int t = threadIdx.x;
    __shared__ int   head[NCLS];
    __shared__ float bv[128];
    __shared__ int   bi[128];
    __shared__ int   bc[128];
    __shared__ float topv[100];
    __shared__ int   topi[100];

    if (t < NCLS) head[t] = 0;
    __syncthreads();

    for (int r = 0; r < 100; r++) {
        float v = -2e30f; int fi = 0x7fffffff;
        if (t < NCLS) {
            int h = head[t];
            if (h < 100) { v = candS[t * 100 + h]; fi = candI[t * 100 + h]; }
        }
        bv[t] = v; bi[t] = fi; bc[t] = t;
        __syncthreads();
        for (int s = 64; s > 0; s >>= 1) {
            if (t < s) {
                float ov = bv[t + s]; int oi = bi[t + s];
                if (ov > bv[t] || (ov == bv[t] && oi < bi[t])) {
                    bv[t] = ov; bi[t] = oi; bc[t] = bc[t + s];
                }
            }
            __syncthreads();
        }
        if (t == 0) {
            topv[r] = bv[0]; topi[r] = bi[0];
            head[bc[0]]++;
        }
        __syncthreads();
    }

    if (t < 100) {
        float v = topv[t]; int fi = topi[t];
        bool valid = v > 0.0f;
        float4 bb = make_float4(0.f, 0.f, 0.f, 0.f);
        if (valid) bb = *(const float4*)&sortedB[(size_t)fi * 4];
        out[1 + t * 4 + 0] = bb.x;
        out[1 + t * 4 + 1] = bb.y;
        out[1 + t * 4 + 2] = bb.z;
        out[1 + t * 4 + 3] = bb.w;
        out[401 + t] = valid ? v : 0.0f;
        out[501 + t] = valid ? (float)(fi / NPROP) : -1.0f;
    }
    if (t == 0) {
        int n = 0;
        for (int r = 0; r < 100; r++) n += (topv[r] > 0.0f) ? 1 : 0;
        out[0] = (float)n;
    }
}

// ---------------------------------------------------------------------------
extern "C" void kernel_launch(void* const* d_in, const int* in_sizes, int n_in,
                              void* d_out, int out_size, void* d_ws, size_t ws_size,
                              hipStream_t stream)
{
    const float* f0    = (const float*)d_in[0];
    const float* f1    = (const float*)d_in[1];
    const float* f2    = (const float*)d_in[2];
    const float* f3    = (const float*)d_in[3];
    const float* props = (const float*)d_in[4];
    const float* fc1_w = (const float*)d_in[5];
    const float* fc1_b = (const float*)d_in[6];
    const float* fc2_w = (const float*)d_in[7];
    const float* fc2_b = (const float*)d_in[8];
    const float* cls_w = (const float*)d_in[9];
    const float* cls_b = (const float*)d_in[10];
    const float* reg_w = (const float*)d_in[11];
    const float* reg_b = (const float*)d_in[12];
    float* out = (float*)d_out;

    // --- workspace carve (peak 61,341,696 B <= proven 63.3 MB) ---
    unsigned char* base = (unsigned char*)d_ws;
    ushort_t* Abf  = (ushort_t*)(base);               // 25,690,112 (dead after fc1)
    ushort_t* h1   = (ushort_t*)(base + 25690112);    //  2,097,152 bf16
    float*    P1   = (float*)(base + 27787264);       // 33,554,432 (SK=8 fc1 partials; dead after reduce1)
    // P2 reuses P1 start (fc1 partials dead):
    float*    P2   = (float*)(base + 27787264);       // 16,777,216 (SK=4 fc2 partials; dead after reduce2)
    float*    h2   = (float*)(base + 44564480);       //  4,194,304 fp32
    // post-GEMM buffers (live after fc2; P2 region dead by then except h2 which is disjoint):
    float*    cls_s   = (float*)(base + 48758784);    //    331,776 (1024x81)
    float*    reg_s   = (float*)(base + 49090560);    //  1,310,720 (1024x320)
    float*    probsT  = (float*)(base + 50401280);    //    320,000
    float*    boxesT  = (float*)(base + 50721280);    //  1,280,000
    float*    sortedS = (float*)(base + 52001280);    //    320,000
    float*    sortedB = (float*)(base + 52321280);    //  1,280,000
    float*    candS   = (float*)(base + 53601280);    //     32,000
    int*      candI   = (int*)(base + 53633280);      //     32,000

    // 1) RoI align -> bf16 A matrix (1024 x 12544, pad rows zeroed)
    roi_align_k<<<MPAD, 256, 0, stream>>>(f0, f1, f2, f3, props, Abf);

    // 2) fc1: split-K=8 (KC=1568=49*32), W converted fp32->bf16 on the fly
    gemm_sk_k<<<dim3(FCDIM / 128, MPAD / 128, 8), 256, 0, stream>>>(
        Abf, fc1_w, P1, FCDIM, DFLAT, DFLAT / 8);
    reduce_sk_k<<<(MPAD * FCDIM / 4) / 256, 256, 0, stream>>>(
        P1, fc1_b, h1, FCDIM, 8, 1, 1);

    // 3) fc2: split-K=4 (KC=256)
    gemm_sk_k<<<dim3(FCDIM / 128, MPAD / 128, 4), 256, 0, stream>>>(
        h1, fc2_w, P2, FCDIM, FCDIM, FCDIM / 4);
    reduce_sk_k<<<(MPAD * FCDIM / 4) / 256, 256, 0, stream>>>(
        P2, fc2_b, h2, FCDIM, 4, 1, 0);

    // 4) heads (fp32)
    gemm_tn_k<<<dim3((81 + 63) / 64, (NPROP + 63) / 64), 256, 0, stream>>>(
        h2, cls_w, cls_b, cls_s, NPROP, 81, FCDIM, 0);
    gemm_tn_k<<<dim3((320 + 63) / 64, (NPROP + 63) / 64), 256, 0, stream>>>(
        h2, reg_w, reg_b, reg_s, NPROP, 320, FCDIM, 0);

    // 5) post-processing
    head_post_k<<<NPROP, 128, 0, stream>>>(cls_s, reg_s, props, probsT, boxesT);
    sort_k<<<NCLS, 512, 0, stream>>>(probsT, boxesT, sortedS, sortedB);
    nms_k<<<NCLS, 256, 0, stream>>>(sortedS, sortedB, candS, candI);
    merge_k<<<1, 128, 0, stream>>>(candS, candI, sortedB, out);
}